// Round 6
// baseline (216.995 us; speedup 1.0000x reference)
//
#include <hip/hip_runtime.h>

// Problem constants (from reference setup_inputs)
#define BB   64          // batch
#define SS   512         // seq len
#define HH   768         // hidden dim
#define WW   256         // MAX_WORD_LEN (words per batch)
#define WE   300         // word-embedding dim
#define OUTD (HH + WE)   // 1068 output feature dim

// mean kernel: token-centric streaming segment-mean
#define NR   32               // token ranges per batch row
#define TR   (SS / NR)        // 16 tokens per block
// w2v kernel
#define WGPB 8                // word-groups per batch row
#define WPB_B (WW / WGPB)     // 32 words per block

// R6: R0-R5 are all pinned at ~2 TB/s (64-73 us) across radically different
// structures; R5 showed occupancy 62%->21% with ZERO time change, falsifying
// pure wave-latency-bound theory: the memory system is throughput-saturated
// at ~2 TB/s for this traffic MIX. Split the two streams into separate
// dispatches to (a) attribute the cap (copy-shaped mean stream vs random
// w2v gather) via per-kernel counters, (b) give the mean kernel full
// occupancy (2048 blocks, 8/CU residency).

// ---------------- kernel 1: segment means -> out[:,:,0:768] ----------------
__global__ __launch_bounds__(256)
void EmbeddingsModule_45311904973549_mean(
    const float* __restrict__ hidden,     // [B, S, H]
    const int*   __restrict__ token_ids,  // [B, S] sorted per row, in [0,W)
    float*       __restrict__ out)        // [B, W, OUTD]
{
    __shared__ int tk[SS];
    __shared__ int LB[WW + 1];    // LB[k] = lower_bound(k) over this row

    const int b   = blockIdx.x / NR;
    const int r   = blockIdx.x % NR;
    const int s0  = r * TR;
    const int tid = threadIdx.x;

    // stage token row (512 ints, int2 per thread) + init LB
    ((int2*)tk)[tid] = ((const int2*)(token_ids + (size_t)b * SS))[tid];
    LB[tid] = SS;
    if (tid == 0) LB[WW] = SS;
    __syncthreads();

    // scatter: position s with t=tk[s], tp=tk[s-1] sets LB[k]=s for k in (tp,t]
    #pragma unroll
    for (int u = 0; u < 2; ++u) {
        const int s  = tid * 2 + u;
        const int t  = tk[s];
        const int tp = (s == 0) ? -1 : tk[s - 1];
        for (int k = tp + 1; k <= t; ++k) LB[k] = s;
    }
    __syncthreads();

    // word range owned by this block: (w_prev, wlast]  (words STARTING here;
    // the last word may continue past s0+TR -> we read to e which can exceed)
    const int w_prev = (r == 0) ? -1 : tk[s0 - 1];
    const int wlast  = (r == NR - 1) ? (WW - 1) : tk[s0 + TR - 1];
    if (wlast == w_prev) return;                 // no words start in this range

    const int s_start = __builtin_amdgcn_readfirstlane(LB[w_prev + 1]);
    const int e       = __builtin_amdgcn_readfirstlane(LB[wlast + 1]);

    if (tid >= 192) return;                      // wave 3: staging only

    float* const outb = out + (size_t)b * WW * OUTD;
    const float4 z4 = make_float4(0.f, 0.f, 0.f, 0.f);

    if (s_start >= SS) {                         // only possible for r==NR-1
        for (int w = w_prev + 1; w <= wlast; ++w)
            ((float4*)(outb + (size_t)w * OUTD))[tid] = z4;
        return;
    }
    {   // leading empty words: (w_prev, tk[s_start])
        const int wfirst = tk[s_start];
        for (int w = w_prev + 1; w < wfirst; ++w)
            ((float4*)(outb + (size_t)w * OUTD))[tid] = z4;
    }

    const float4* hrow = (const float4*)(hidden + (size_t)b * SS * HH);
    float4 acc = z4;
    int    cnt = 0;
    const int sb0 = s_start & ~7;                // align batches to 8 rows

    for (int sb = sb0; sb < e; sb += 8) {
        // --- 8 independent streaming loads (pure induction addresses)
        float4 v[8];
        #pragma unroll
        for (int j = 0; j < 8; ++j) {
            int s = sb + j; s = (s < e) ? s : (e - 1);   // in-bounds reread
            v[j] = hrow[(size_t)s * (HH / 4) + tid];
        }
        int tok[9];
        #pragma unroll
        for (int j = 0; j < 9; ++j) {
            int s = sb + j; tok[j] = tk[(s < SS) ? s : (SS - 1)];
        }
        __builtin_amdgcn_sched_barrier(0);   // consume may not move above
        // --- consume: accumulate + uniform flush/zero-fill
        #pragma unroll
        for (int j = 0; j < 8; ++j) {
            const int s = sb + j;
            if (s >= s_start && s < e) {
                acc.x += v[j].x; acc.y += v[j].y; acc.z += v[j].z; acc.w += v[j].w;
                ++cnt;
                const bool fl = (s + 1 == e) || (tok[j + 1] != tok[j]);
                if (fl) {
                    const float inv = 1.0f / (float)cnt;
                    float4 o = make_float4(acc.x * inv, acc.y * inv,
                                           acc.z * inv, acc.w * inv);
                    ((float4*)(outb + (size_t)tok[j] * OUTD))[tid] = o;
                    acc = z4; cnt = 0;
                    const int wnext = (s + 1 < e) ? tok[j + 1] : (wlast + 1);
                    for (int w = tok[j] + 1; w < wnext; ++w)
                        ((float4*)(outb + (size_t)w * OUTD))[tid] = z4;
                }
            }
        }
    }
}

// ---------------- kernel 2: w2v gather -> out[:,:,768:1068] ----------------
__global__ __launch_bounds__(256)
void EmbeddingsModule_45311904973549_w2v(
    const float* __restrict__ w2v,        // [VOCAB, WE]
    const int*   __restrict__ word_ids,   // [B, W] in [0,VOCAB)
    float*       __restrict__ out)        // [B, W, OUTD]
{
    const int blk = blockIdx.x;
    const int tid = threadIdx.x;
    const int b   = blk / WGPB;
    const int w   = (blk % WGPB) * WPB_B + (tid >> 3);  // 32 words x 8 lanes
    const int l   = tid & 7;
    const int wid = word_ids[b * WW + w];
    const float4* src = (const float4*)(w2v + (size_t)wid * WE);
    float4*       dst = (float4*)(out + (size_t)(b * WW + w) * OUTD + HH);
    float4 t[10];
    #pragma unroll
    for (int i = 0; i < 9; ++i) t[i] = src[l + 8 * i];   // j = 0..71
    if (l < 3) t[9] = src[72 + l];                       // j = 72..74
    #pragma unroll
    for (int i = 0; i < 9; ++i) dst[l + 8 * i] = t[i];
    if (l < 3) dst[72 + l] = t[9];
}

extern "C" void kernel_launch(void* const* d_in, const int* in_sizes, int n_in,
                              void* d_out, int out_size, void* d_ws, size_t ws_size,
                              hipStream_t stream) {
    const float* hidden    = (const float*)d_in[0];
    const float* w2v       = (const float*)d_in[1];
    const int*   token_ids = (const int*)d_in[2];
    const int*   word_ids  = (const int*)d_in[3];
    float*       out       = (float*)d_out;

    EmbeddingsModule_45311904973549_mean<<<BB * NR, 256, 0, stream>>>(
        hidden, token_ids, out);
    EmbeddingsModule_45311904973549_w2v<<<BB * WGPB, 256, 0, stream>>>(
        w2v, word_ids, out);
}